// Round 1
// baseline (2622.440 us; speedup 1.0000x reference)
//
#include <hip/hip_runtime.h>

#define NTYPES 6
#define HID 128
#define E_TILE 64
#define BK 32

// ws layout (ints): [0..5] counts, [8..14] offsets, [16..21] cursors, [32..32+E) sorted edge ids

__global__ void k_init(int* __restrict__ ws) {
    int i = threadIdx.x;
    if (i < NTYPES) { ws[i] = 0; ws[16 + i] = 0; }
}

__global__ void k_hist(const int* __restrict__ etype, int E, int* __restrict__ ws) {
    int i = blockIdx.x * blockDim.x + threadIdx.x;
    if (i < E) atomicAdd(&ws[etype[i] - 1], 1);
}

__global__ void k_prefix(int* __restrict__ ws) {
    if (threadIdx.x == 0 && blockIdx.x == 0) {
        int acc = 0;
        for (int t = 0; t < NTYPES; ++t) { ws[8 + t] = acc; acc += ws[t]; }
        ws[8 + NTYPES] = acc;
    }
}

__global__ void k_fill(const int* __restrict__ etype, int E, int* __restrict__ ws) {
    int i = blockIdx.x * blockDim.x + threadIdx.x;
    if (i < E) {
        int t = etype[i] - 1;
        int pos = atomicAdd(&ws[16 + t], 1);
        ws[32 + ws[8 + t] + pos] = i;
    }
}

// One block = 64 edges of a single type. 256 threads.
// Per thread: 4 edges x 8 cols register tile -> 32 f32 accumulators.
__launch_bounds__(256, 4)
__global__ void k_edge_gemm(const float* __restrict__ state,
                            const int* __restrict__ src,
                            const int* __restrict__ tgt,
                            const float* __restrict__ W,
                            const int* __restrict__ ws,
                            float* __restrict__ out) {
    // LDS: XsT (32 x 65) + Wsh (32 x 132) both fit inside the 64x128 Os buffer
    __shared__ float lds[E_TILE * HID];         // 32 KB
    __shared__ int sN[E_TILE];
    __shared__ int tN[E_TILE];

    float (*XsT)[E_TILE + 1] = (float (*)[E_TILE + 1])lds;                       // 32x65 = 2080 floats
    float (*Wsh)[HID + 4]    = (float (*)[HID + 4])(lds + BK * (E_TILE + 1));    // 32x132 = 4224 floats
    float (*Os)[HID]         = (float (*)[HID])lds;                              // 64x128 (reuse)

    const int* offs   = ws + 8;
    const int* sorted = ws + 32;

    // map blockIdx -> (type, tile-within-type)
    int tile = blockIdx.x;
    int ty, base = 0, cnt = 0;
    for (ty = 0; ty < NTYPES; ++ty) {
        int b = offs[ty], oend = offs[ty + 1];
        int nt = (oend - b + E_TILE - 1) / E_TILE;
        if (tile < nt) {
            base = b + tile * E_TILE;
            cnt = oend - base;
            if (cnt > E_TILE) cnt = E_TILE;
            break;
        }
        tile -= nt;
    }
    if (ty == NTYPES) return;

    int tid = threadIdx.x;
    if (tid < E_TILE) {
        int sn = 0, tn = 0;
        if (tid < cnt) { int e = sorted[base + tid]; sn = src[e]; tn = tgt[e]; }
        sN[tid] = sn; tN[tid] = tn;
    }

    const float* Wt = W + (size_t)ty * (2 * HID) * HID;

    float acc[4][8];
    #pragma unroll
    for (int i = 0; i < 4; ++i)
        #pragma unroll
        for (int j = 0; j < 8; ++j) acc[i][j] = 0.f;

    const int te = tid & 15;      // edge group: edges te*4 .. te*4+3
    const int tc = tid >> 4;      // col group:  cols tc*8 .. tc*8+7
    const int eload = tid >> 2;   // 0..63 edge for X staging
    const int qload = tid & 3;    // 0..3 float4 slot
    const int wj = tid & 31;      // float4 col for W staging
    const int wk = tid >> 5;      // row group for W staging

    for (int kk = 0; kk < 8; ++kk) {
        const int k0 = kk * BK;
        const int col0 = k0 & (HID - 1);
        __syncthreads();   // protects LDS from previous-iter readers (and covers sN/tN on kk=0)

        // stage X^T: XsT[k][edge], k in [0,32)
        {
            const int node = (k0 < HID) ? sN[eload] : tN[eload];
            const float* rp = state + (size_t)node * HID + col0;
            float4 v0 = *(const float4*)(rp + qload * 4);
            float4 v1 = *(const float4*)(rp + 16 + qload * 4);
            if (eload >= cnt) { v0 = make_float4(0.f, 0.f, 0.f, 0.f); v1 = v0; }
            const int kb = qload * 4;
            XsT[kb + 0][eload] = v0.x;
            XsT[kb + 1][eload] = v0.y;
            XsT[kb + 2][eload] = v0.z;
            XsT[kb + 3][eload] = v0.w;
            XsT[kb + 16][eload] = v1.x;
            XsT[kb + 17][eload] = v1.y;
            XsT[kb + 18][eload] = v1.z;
            XsT[kb + 19][eload] = v1.w;
        }
        // stage W rows k0..k0+31 (coalesced float4, L2-hot)
        {
            const float* wp = Wt + (size_t)k0 * HID;
            #pragma unroll
            for (int r = 0; r < 4; ++r) {
                int k = wk + r * 8;
                *(float4*)&Wsh[k][wj * 4] = *(const float4*)(wp + (size_t)k * HID + wj * 4);
            }
        }
        __syncthreads();

        #pragma unroll
        for (int k = 0; k < BK; ++k) {
            float x0 = XsT[k][te * 4 + 0];
            float x1 = XsT[k][te * 4 + 1];
            float x2 = XsT[k][te * 4 + 2];
            float x3 = XsT[k][te * 4 + 3];
            float4 w0 = *(const float4*)&Wsh[k][tc * 8];
            float4 w1 = *(const float4*)&Wsh[k][tc * 8 + 4];
            acc[0][0] += x0 * w0.x; acc[0][1] += x0 * w0.y; acc[0][2] += x0 * w0.z; acc[0][3] += x0 * w0.w;
            acc[0][4] += x0 * w1.x; acc[0][5] += x0 * w1.y; acc[0][6] += x0 * w1.z; acc[0][7] += x0 * w1.w;
            acc[1][0] += x1 * w0.x; acc[1][1] += x1 * w0.y; acc[1][2] += x1 * w0.z; acc[1][3] += x1 * w0.w;
            acc[1][4] += x1 * w1.x; acc[1][5] += x1 * w1.y; acc[1][6] += x1 * w1.z; acc[1][7] += x1 * w1.w;
            acc[2][0] += x2 * w0.x; acc[2][1] += x2 * w0.y; acc[2][2] += x2 * w0.z; acc[2][3] += x2 * w0.w;
            acc[2][4] += x2 * w1.x; acc[2][5] += x2 * w1.y; acc[2][6] += x2 * w1.z; acc[2][7] += x2 * w1.w;
            acc[3][0] += x3 * w0.x; acc[3][1] += x3 * w0.y; acc[3][2] += x3 * w0.z; acc[3][3] += x3 * w0.w;
            acc[3][4] += x3 * w1.x; acc[3][5] += x3 * w1.y; acc[3][6] += x3 * w1.z; acc[3][7] += x3 * w1.w;
        }
    }

    // stage messages to LDS, then coalesced scatter-add (128 consecutive floats per edge row)
    __syncthreads();
    #pragma unroll
    for (int i = 0; i < 4; ++i) {
        *(float4*)&Os[te * 4 + i][tc * 8]     = make_float4(acc[i][0], acc[i][1], acc[i][2], acc[i][3]);
        *(float4*)&Os[te * 4 + i][tc * 8 + 4] = make_float4(acc[i][4], acc[i][5], acc[i][6], acc[i][7]);
    }
    __syncthreads();

    const int erow = tid >> 7;         // 0..1
    const int c    = tid & (HID - 1);  // 0..127
    for (int it = 0; it < E_TILE / 2; ++it) {
        int e = it * 2 + erow;
        if (e < cnt) atomicAdd(&out[(size_t)tN[e] * HID + c], Os[e][c]);
    }
}

extern "C" void kernel_launch(void* const* d_in, const int* in_sizes, int n_in,
                              void* d_out, int out_size, void* d_ws, size_t ws_size,
                              hipStream_t stream) {
    const float* state = (const float*)d_in[0];
    const int*   edges = (const int*)d_in[1];
    const float* W     = (const float*)d_in[2];
    float* out = (float*)d_out;

    const int E = in_sizes[1] / 3;
    const int* etype = edges;
    const int* src   = edges + E;
    const int* tgt   = edges + 2 * E;
    int* ws = (int*)d_ws;

    hipMemsetAsync(d_out, 0, (size_t)out_size * sizeof(float), stream);
    k_init<<<1, 64, 0, stream>>>(ws);
    k_hist<<<(E + 255) / 256, 256, 0, stream>>>(etype, E, ws);
    k_prefix<<<1, 1, 0, stream>>>(ws);
    k_fill<<<(E + 255) / 256, 256, 0, stream>>>(etype, E, ws);

    const int nblocks = (E + E_TILE - 1) / E_TILE + NTYPES;
    k_edge_gemm<<<nblocks, 256, 0, stream>>>(state, src, tgt, W, ws, out);
}

// Round 2
// 260.893 us; speedup vs baseline: 10.0518x; 10.0518x over previous
//
#include <hip/hip_runtime.h>

#define NTYPES 6
#define HID 128
#define E_TILE 64
#define BK 32

// ws layout (ints): [0..5] counts, [8..14] offsets, [16..21] cursors, [32..32+E) sorted edge ids

__global__ void k_init(int* __restrict__ ws) {
    int i = threadIdx.x;
    if (i < NTYPES) { ws[i] = 0; ws[16 + i] = 0; }
}

// per-block LDS histogram -> 6 global atomics per block
__global__ void k_hist(const int* __restrict__ etype, int E, int* __restrict__ ws) {
    __shared__ int h[NTYPES];
    if (threadIdx.x < NTYPES) h[threadIdx.x] = 0;
    __syncthreads();
    int i = blockIdx.x * blockDim.x + threadIdx.x;
    if (i < E) atomicAdd(&h[etype[i] - 1], 1);
    __syncthreads();
    if (threadIdx.x < NTYPES) {
        int c = h[threadIdx.x];
        if (c) atomicAdd(&ws[threadIdx.x], c);
    }
}

__global__ void k_prefix(int* __restrict__ ws) {
    if (threadIdx.x == 0 && blockIdx.x == 0) {
        int acc = 0;
        for (int t = 0; t < NTYPES; ++t) { ws[8 + t] = acc; acc += ws[t]; }
        ws[8 + NTYPES] = acc;
    }
}

// LDS-atomic local rank + per-block cursor reservation (6 global atomics/block)
__global__ void k_fill(const int* __restrict__ etype, int E, int* __restrict__ ws) {
    __shared__ int lcnt[NTYPES];
    __shared__ int lbase[NTYPES];
    if (threadIdx.x < NTYPES) lcnt[threadIdx.x] = 0;
    __syncthreads();
    int i = blockIdx.x * blockDim.x + threadIdx.x;
    int t = 0, lr = 0;
    bool valid = (i < E);
    if (valid) {
        t = etype[i] - 1;
        lr = atomicAdd(&lcnt[t], 1);
    }
    __syncthreads();
    if (threadIdx.x < NTYPES) {
        int c = lcnt[threadIdx.x];
        lbase[threadIdx.x] = c ? atomicAdd(&ws[16 + threadIdx.x], c) : 0;
    }
    __syncthreads();
    if (valid) ws[32 + ws[8 + t] + lbase[t] + lr] = i;
}

// One block = 64 edges of a single type. 256 threads.
// Per thread: 4 edges x 8 cols register tile -> 32 f32 accumulators.
__launch_bounds__(256, 4)
__global__ void k_edge_gemm(const float* __restrict__ state,
                            const int* __restrict__ src,
                            const int* __restrict__ tgt,
                            const float* __restrict__ W,
                            const int* __restrict__ ws,
                            float* __restrict__ out) {
    // LDS: XsT (32 x 65) + Wsh (32 x 132) both fit inside the 64x128 Os buffer
    __shared__ float lds[E_TILE * HID];         // 32 KB
    __shared__ int sN[E_TILE];
    __shared__ int tN[E_TILE];

    float (*XsT)[E_TILE + 1] = (float (*)[E_TILE + 1])lds;                       // 32x65 = 2080 floats
    float (*Wsh)[HID + 4]    = (float (*)[HID + 4])(lds + BK * (E_TILE + 1));    // 32x132 = 4224 floats
    float (*Os)[HID]         = (float (*)[HID])lds;                              // 64x128 (reuse)

    const int* offs   = ws + 8;
    const int* sorted = ws + 32;

    // map blockIdx -> (type, tile-within-type)
    int tile = blockIdx.x;
    int ty, base = 0, cnt = 0;
    for (ty = 0; ty < NTYPES; ++ty) {
        int b = offs[ty], oend = offs[ty + 1];
        int nt = (oend - b + E_TILE - 1) / E_TILE;
        if (tile < nt) {
            base = b + tile * E_TILE;
            cnt = oend - base;
            if (cnt > E_TILE) cnt = E_TILE;
            break;
        }
        tile -= nt;
    }
    if (ty == NTYPES) return;

    int tid = threadIdx.x;
    if (tid < E_TILE) {
        int sn = 0, tn = 0;
        if (tid < cnt) { int e = sorted[base + tid]; sn = src[e]; tn = tgt[e]; }
        sN[tid] = sn; tN[tid] = tn;
    }

    const float* Wt = W + (size_t)ty * (2 * HID) * HID;

    float acc[4][8];
    #pragma unroll
    for (int i = 0; i < 4; ++i)
        #pragma unroll
        for (int j = 0; j < 8; ++j) acc[i][j] = 0.f;

    const int te = tid & 15;      // edge group: edges te*4 .. te*4+3
    const int tc = tid >> 4;      // col group:  cols tc*8 .. tc*8+7
    const int eload = tid >> 2;   // 0..63 edge for X staging
    const int qload = tid & 3;    // 0..3 float4 slot
    const int wj = tid & 31;      // float4 col for W staging
    const int wk = tid >> 5;      // row group for W staging

    for (int kk = 0; kk < 8; ++kk) {
        const int k0 = kk * BK;
        const int col0 = k0 & (HID - 1);
        __syncthreads();   // protects LDS from previous-iter readers (and covers sN/tN on kk=0)

        // stage X^T: XsT[k][edge], k in [0,32)
        {
            const int node = (k0 < HID) ? sN[eload] : tN[eload];
            const float* rp = state + (size_t)node * HID + col0;
            float4 v0 = *(const float4*)(rp + qload * 4);
            float4 v1 = *(const float4*)(rp + 16 + qload * 4);
            if (eload >= cnt) { v0 = make_float4(0.f, 0.f, 0.f, 0.f); v1 = v0; }
            const int kb = qload * 4;
            XsT[kb + 0][eload] = v0.x;
            XsT[kb + 1][eload] = v0.y;
            XsT[kb + 2][eload] = v0.z;
            XsT[kb + 3][eload] = v0.w;
            XsT[kb + 16][eload] = v1.x;
            XsT[kb + 17][eload] = v1.y;
            XsT[kb + 18][eload] = v1.z;
            XsT[kb + 19][eload] = v1.w;
        }
        // stage W rows k0..k0+31 (coalesced float4, L2-hot)
        {
            const float* wp = Wt + (size_t)k0 * HID;
            #pragma unroll
            for (int r = 0; r < 4; ++r) {
                int k = wk + r * 8;
                *(float4*)&Wsh[k][wj * 4] = *(const float4*)(wp + (size_t)k * HID + wj * 4);
            }
        }
        __syncthreads();

        #pragma unroll
        for (int k = 0; k < BK; ++k) {
            float x0 = XsT[k][te * 4 + 0];
            float x1 = XsT[k][te * 4 + 1];
            float x2 = XsT[k][te * 4 + 2];
            float x3 = XsT[k][te * 4 + 3];
            float4 w0 = *(const float4*)&Wsh[k][tc * 8];
            float4 w1 = *(const float4*)&Wsh[k][tc * 8 + 4];
            acc[0][0] += x0 * w0.x; acc[0][1] += x0 * w0.y; acc[0][2] += x0 * w0.z; acc[0][3] += x0 * w0.w;
            acc[0][4] += x0 * w1.x; acc[0][5] += x0 * w1.y; acc[0][6] += x0 * w1.z; acc[0][7] += x0 * w1.w;
            acc[1][0] += x1 * w0.x; acc[1][1] += x1 * w0.y; acc[1][2] += x1 * w0.z; acc[1][3] += x1 * w0.w;
            acc[1][4] += x1 * w1.x; acc[1][5] += x1 * w1.y; acc[1][6] += x1 * w1.z; acc[1][7] += x1 * w1.w;
            acc[2][0] += x2 * w0.x; acc[2][1] += x2 * w0.y; acc[2][2] += x2 * w0.z; acc[2][3] += x2 * w0.w;
            acc[2][4] += x2 * w1.x; acc[2][5] += x2 * w1.y; acc[2][6] += x2 * w1.z; acc[2][7] += x2 * w1.w;
            acc[3][0] += x3 * w0.x; acc[3][1] += x3 * w0.y; acc[3][2] += x3 * w0.z; acc[3][3] += x3 * w0.w;
            acc[3][4] += x3 * w1.x; acc[3][5] += x3 * w1.y; acc[3][6] += x3 * w1.z; acc[3][7] += x3 * w1.w;
        }
    }

    // stage messages to LDS, then coalesced scatter-add (128 consecutive floats per edge row)
    __syncthreads();
    #pragma unroll
    for (int i = 0; i < 4; ++i) {
        *(float4*)&Os[te * 4 + i][tc * 8]     = make_float4(acc[i][0], acc[i][1], acc[i][2], acc[i][3]);
        *(float4*)&Os[te * 4 + i][tc * 8 + 4] = make_float4(acc[i][4], acc[i][5], acc[i][6], acc[i][7]);
    }
    __syncthreads();

    const int erow = tid >> 7;         // 0..1
    const int c    = tid & (HID - 1);  // 0..127
    for (int it = 0; it < E_TILE / 2; ++it) {
        int e = it * 2 + erow;
        if (e < cnt) atomicAdd(&out[(size_t)tN[e] * HID + c], Os[e][c]);
    }
}

extern "C" void kernel_launch(void* const* d_in, const int* in_sizes, int n_in,
                              void* d_out, int out_size, void* d_ws, size_t ws_size,
                              hipStream_t stream) {
    const float* state = (const float*)d_in[0];
    const int*   edges = (const int*)d_in[1];
    const float* W     = (const float*)d_in[2];
    float* out = (float*)d_out;

    const int E = in_sizes[1] / 3;
    const int* etype = edges;
    const int* src   = edges + E;
    const int* tgt   = edges + 2 * E;
    int* ws = (int*)d_ws;

    hipMemsetAsync(d_out, 0, (size_t)out_size * sizeof(float), stream);
    k_init<<<1, 64, 0, stream>>>(ws);
    k_hist<<<(E + 255) / 256, 256, 0, stream>>>(etype, E, ws);
    k_prefix<<<1, 1, 0, stream>>>(ws);
    k_fill<<<(E + 255) / 256, 256, 0, stream>>>(etype, E, ws);

    const int nblocks = (E + E_TILE - 1) / E_TILE + NTYPES;
    k_edge_gemm<<<nblocks, 256, 0, stream>>>(state, src, tgt, W, ws, out);
}

// Round 3
// 168.216 us; speedup vs baseline: 15.5898x; 1.5509x over previous
//
#include <hip/hip_runtime.h>

#define NTYPES 6
#define HID 128
#define E_TILE 64

typedef short short8 __attribute__((ext_vector_type(8)));
typedef float f32x4 __attribute__((ext_vector_type(4)));

// ws layout: ints [0..5] counts, [8..14] offsets, [16..21] cursors,
// [32..32+E) sorted edge ids; then 256B-aligned: Wt bf16 [6][128][256]

static __device__ __forceinline__ ushort f2bf(float f) {
    union { float f; unsigned u; } v; v.f = f;
    unsigned r = v.u + 0x7FFFu + ((v.u >> 16) & 1u);   // RNE
    return (ushort)(r >> 16);
}

__global__ void k_init(int* __restrict__ ws) {
    int i = threadIdx.x;
    if (i < NTYPES) { ws[i] = 0; ws[16 + i] = 0; }
}

__global__ void k_hist(const int* __restrict__ etype, int E, int* __restrict__ ws) {
    __shared__ int h[NTYPES];
    if (threadIdx.x < NTYPES) h[threadIdx.x] = 0;
    __syncthreads();
    int i = blockIdx.x * blockDim.x + threadIdx.x;
    if (i < E) atomicAdd(&h[etype[i] - 1], 1);
    __syncthreads();
    if (threadIdx.x < NTYPES) {
        int c = h[threadIdx.x];
        if (c) atomicAdd(&ws[threadIdx.x], c);
    }
}

__global__ void k_prefix(int* __restrict__ ws) {
    if (threadIdx.x == 0 && blockIdx.x == 0) {
        int acc = 0;
        for (int t = 0; t < NTYPES; ++t) { ws[8 + t] = acc; acc += ws[t]; }
        ws[8 + NTYPES] = acc;
    }
}

__global__ void k_fill(const int* __restrict__ etype, int E, int* __restrict__ ws) {
    __shared__ int lcnt[NTYPES];
    __shared__ int lbase[NTYPES];
    if (threadIdx.x < NTYPES) lcnt[threadIdx.x] = 0;
    __syncthreads();
    int i = blockIdx.x * blockDim.x + threadIdx.x;
    int t = 0, lr = 0;
    bool valid = (i < E);
    if (valid) {
        t = etype[i] - 1;
        lr = atomicAdd(&lcnt[t], 1);
    }
    __syncthreads();
    if (threadIdx.x < NTYPES) {
        int c = lcnt[threadIdx.x];
        lbase[threadIdx.x] = c ? atomicAdd(&ws[16 + threadIdx.x], c) : 0;
    }
    __syncthreads();
    if (valid) ws[32 + ws[8 + t] + lbase[t] + lr] = i;
}

// W f32 [6][256][128] -> Wt bf16 [6][128][256] (transposed per type)
__global__ void k_wconv(const float* __restrict__ W, ushort* __restrict__ Wt) {
    int t = blockIdx.x * blockDim.x + threadIdx.x;   // 6*128*32 threads
    int n  = t & 127;
    int k8 = (t >> 7) & 31;
    int ty = t >> 12;
    if (ty >= NTYPES) return;
    const float* wp = W + ((size_t)ty * 256 + (size_t)k8 * 8) * HID + n;
    ushort tmp[8];
    #pragma unroll
    for (int j = 0; j < 8; ++j) tmp[j] = f2bf(wp[(size_t)j * HID]);
    *(short8*)(Wt + ((size_t)ty * HID + n) * 256 + k8 * 8) = *(short8*)tmp;
}

// One block = 64 edges of one type x 128 output cols, K=256 via MFMA bf16.
// 4 waves; wave w owns cols [w*32, w*32+32). No syncthreads in the K-loop.
__launch_bounds__(256, 4)
__global__ void k_edge_gemm(const float* __restrict__ state,
                            const int* __restrict__ src,
                            const int* __restrict__ tgt,
                            const ushort* __restrict__ Wt,
                            const int* __restrict__ ws,
                            float* __restrict__ out) {
    __shared__ __align__(16) ushort Xs[E_TILE][264];   // 33792 B, pad +8 bf16
    __shared__ int sN[E_TILE];
    __shared__ int tN[E_TILE];

    const int* offs   = ws + 8;
    const int* sorted = ws + 32;

    // map blockIdx -> (type, tile-within-type)
    int tile = blockIdx.x;
    int ty, base = 0, cnt = 0;
    for (ty = 0; ty < NTYPES; ++ty) {
        int b = offs[ty], oend = offs[ty + 1];
        int nt = (oend - b + E_TILE - 1) / E_TILE;
        if (tile < nt) {
            base = b + tile * E_TILE;
            cnt = oend - base;
            if (cnt > E_TILE) cnt = E_TILE;
            break;
        }
        tile -= nt;
    }
    if (ty == NTYPES) return;

    const int tid = threadIdx.x;
    if (tid < E_TILE) {
        int sn = 0, tn = 0;
        if (tid < cnt) { int e = sorted[base + tid]; sn = src[e]; tn = tgt[e]; }
        sN[tid] = sn; tN[tid] = tn;
    }
    __syncthreads();

    // ---- stage X = [state[src] | state[tgt]] as bf16 [64][256] ----
    {
        const int e = tid >> 2, q = tid & 3;          // 4 threads per edge
        if (e < cnt) {
            #pragma unroll
            for (int h = 0; h < 2; ++h) {
                const int node = h ? tN[e] : sN[e];
                const float* rp = state + (size_t)node * HID + q * 32;
                #pragma unroll
                for (int i = 0; i < 4; ++i) {
                    float4 v0 = *(const float4*)(rp + i * 8);
                    float4 v1 = *(const float4*)(rp + i * 8 + 4);
                    ushort tmp[8] = { f2bf(v0.x), f2bf(v0.y), f2bf(v0.z), f2bf(v0.w),
                                      f2bf(v1.x), f2bf(v1.y), f2bf(v1.z), f2bf(v1.w) };
                    *(short8*)&Xs[e][h * HID + q * 32 + i * 8] = *(short8*)tmp;
                }
            }
        } else {
            short8 z = (short8){0, 0, 0, 0, 0, 0, 0, 0};
            #pragma unroll
            for (int h = 0; h < 2; ++h)
                #pragma unroll
                for (int i = 0; i < 4; ++i)
                    *(short8*)&Xs[e][h * HID + q * 32 + i * 8] = z;
        }
    }
    __syncthreads();

    // ---- MFMA: wave w computes edges 0..63 x cols w*32..w*32+31 ----
    const int w  = tid >> 6;
    const int l  = tid & 63;
    const int lr = l & 15;
    const int lg = l >> 4;

    f32x4 acc[4][2];
    #pragma unroll
    for (int mf = 0; mf < 4; ++mf)
        #pragma unroll
        for (int nf = 0; nf < 2; ++nf)
            acc[mf][nf] = (f32x4){0.f, 0.f, 0.f, 0.f};

    // B-frag base: Wt[ty][w*32 + lr][8*lg]  (direct global, L2-hot)
    const ushort* wb = Wt + ((size_t)ty * HID + w * 32 + lr) * 256 + 8 * lg;
    const ushort* xb = &Xs[lr][8 * lg];

    #pragma unroll
    for (int kk = 0; kk < 8; ++kk) {
        const int k0 = kk * 32;
        short8 b0 = *(const short8*)(wb + k0);             // nf=0
        short8 b1 = *(const short8*)(wb + 16 * 256 + k0);  // nf=1
        #pragma unroll
        for (int mf = 0; mf < 4; ++mf) {
            short8 a = *(const short8*)(xb + mf * 16 * 264 + k0);
            acc[mf][0] = __builtin_amdgcn_mfma_f32_16x16x32_bf16(a, b0, acc[mf][0], 0, 0, 0);
            acc[mf][1] = __builtin_amdgcn_mfma_f32_16x16x32_bf16(a, b1, acc[mf][1], 0, 0, 0);
        }
    }

    // ---- epilogue: acc -> Os (overlay on Xs), then coalesced scatter-add ----
    __syncthreads();
    float (*Os)[HID] = (float (*)[HID])&Xs[0][0];   // 32 KB <= 33.8 KB
    #pragma unroll
    for (int mf = 0; mf < 4; ++mf)
        #pragma unroll
        for (int nf = 0; nf < 2; ++nf)
            #pragma unroll
            for (int r = 0; r < 4; ++r)
                Os[mf * 16 + lg * 4 + r][w * 32 + nf * 16 + lr] = acc[mf][nf][r];
    __syncthreads();

    const int erow = tid >> 7;         // 0..1
    const int c    = tid & (HID - 1);  // 0..127
    for (int it = 0; it < E_TILE / 2; ++it) {
        int ee = it * 2 + erow;
        if (ee < cnt) atomicAdd(&out[(size_t)tN[ee] * HID + c], Os[ee][c]);
    }
}

extern "C" void kernel_launch(void* const* d_in, const int* in_sizes, int n_in,
                              void* d_out, int out_size, void* d_ws, size_t ws_size,
                              hipStream_t stream) {
    const float* state = (const float*)d_in[0];
    const int*   edges = (const int*)d_in[1];
    const float* W     = (const float*)d_in[2];
    float* out = (float*)d_out;

    const int E = in_sizes[1] / 3;
    const int* etype = edges;
    const int* src   = edges + E;
    const int* tgt   = edges + 2 * E;
    int* ws = (int*)d_ws;

    const size_t wt_off = (((size_t)(32 + E) * sizeof(int)) + 255) & ~(size_t)255;
    ushort* Wt = (ushort*)((char*)d_ws + wt_off);

    hipMemsetAsync(d_out, 0, (size_t)out_size * sizeof(float), stream);
    k_init<<<1, 64, 0, stream>>>(ws);
    k_hist<<<(E + 255) / 256, 256, 0, stream>>>(etype, E, ws);
    k_prefix<<<1, 1, 0, stream>>>(ws);
    k_fill<<<(E + 255) / 256, 256, 0, stream>>>(etype, E, ws);
    k_wconv<<<(NTYPES * HID * 32) / 256, 256, 0, stream>>>(W, Wt);

    const int nblocks = (E + E_TILE - 1) / E_TILE + NTYPES;
    k_edge_gemm<<<nblocks, 256, 0, stream>>>(state, src, tgt, Wt, ws, out);
}